// Round 1
// baseline (788.417 us; speedup 1.0000x reference)
//
#include <hip/hip_runtime.h>

// Problem constants (fixed by setup_inputs)
#define BB 4
#define SS 8
#define CC 3
#define HH 1024
#define WW 1024
#define TH 32
#define TW 64
#define GSH (TH + 8)   // 40 gray rows  (halo 4)
#define GSW (TW + 8)   // 72 gray cols
#define BLH (TH + 4)   // 36 blurred rows (halo 2)
#define BLW (TW + 4)   // 68 blurred cols
// fused-blur strip decomposition: 3 strips x 12 bl rows, each needs 16 hb rows
#define NSTRIP 3
#define RBS 12
#define HBS (RBS + 4)          // 16
#define NSLOT (NSTRIP * BLW)   // 204 active threads in blur phase

__device__ __forceinline__ int refl(int i, int n) {
    // reflect-101 (jnp 'reflect'), valid for i in [-(n-1), 2n-2]
    i = (i < 0) ? -i : i;
    i = (i >= n) ? (2 * n - 2 - i) : i;
    return i;
}

// Numerics contract (proven absmax==0.0 by previous session, preserved EXACTLY):
//   gray  = ((c0+c1)+c2)/3  in f32
//   hb[r] = sum_{j=0..4} (f64)gs[r][c+j]*GA[j]      (ascending j, f64)
//   bl    = (f32) sum_{i=0..4} hb[r+i]*GA[i]        (ascending i, f64)
//   lap   = (f32) sum over (di row-major, dj) of (f64)bl*LW, zeros skipped
// This version only changes WHERE hb lives (registers, not LDS) — identical
// values in identical order -> bitwise identical output.
__global__ __launch_bounds__(256, 6)
void lap_focus_fused(const float* __restrict__ x, float* __restrict__ out) {
    const int tile = blockIdx.x;     // 0..2047
    const int b  = tile >> 9;
    const int t  = tile & 511;
    const int tr = t >> 4;
    const int tc = t & 15;
    const int r0 = tr * TH;
    const int c0 = tc * TW;

    __shared__ float gs[GSH][GSW];   // grayscale (f32)
    __shared__ float bl[BLH][BLW];   // blurred, rounded to f32 (stage boundary)

    const int tid = threadIdx.x;
    const int tx = tid & 63;
    const int ty = tid >> 6;         // 0..3; thread owns rows ty, ty+4, ..., ty+28

    float best[8];
    int   bidx[8];
#pragma unroll
    for (int m = 0; m < 8; ++m) { best[m] = -3.0e38f; bidx[m] = 0; }

    // g1 = [1,4,6,4,1]/16 — exact dyadics
    const double GA[5] = {0.0625, 0.25, 0.375, 0.25, 0.0625};
    // Laplacian ksize=5: outer(S,D2)+outer(D2,S) — exact integer weights
    const double LW[5][5] = {
        { 2.,  4.,   4.,  4.,  2.},
        { 4.,  0.,  -8.,  0.,  4.},
        { 4., -8., -24., -8.,  4.},
        { 4.,  0.,  -8.,  0.,  4.},
        { 2.,  4.,   4.,  4.,  2.},
    };

    // column indices into bl for the 5 horizontal lap taps (image-edge reflect)
    int ccol[5];
#pragma unroll
    for (int dj = 0; dj < 5; ++dj)
        ccol[dj] = refl(c0 + tx + dj - 2, WW) - c0 + 2;

    // blur-phase slot: thread -> (strip, column). 204 of 256 threads active.
    const bool slot_active = (tid < NSLOT);
    const int strip = tid / BLW;            // 0..2 for active threads
    const int scol  = tid - strip * BLW;    // 0..67
    const int hr0   = strip * RBS;          // base hb/bl row of this strip

    const size_t HW = (size_t)HH * WW;

    // ---- gray loader: tile + halo(4); f32 ((c0+c1)+c2)/3 (np.mean) ----
    auto load_gray = [&](int s) {
        const float* xs = x + (size_t)((b * SS + s) * CC) * HW;
        for (int e = tid; e < GSH * GSW; e += 256) {
            int r = e / GSW;
            int c = e - r * GSW;
            int gi = refl(r0 + r - 4, HH);
            int gj = refl(c0 + c - 4, WW);
            size_t off = (size_t)gi * WW + gj;
            float v = (xs[off] + xs[HW + off]) + xs[2 * HW + off];
            gs[r][c] = v / 3.0f;
        }
    };

    load_gray(0);
    __syncthreads();

    for (int s = 0; s < SS; ++s) {
        // ---- fused separable Gaussian: gs -> bl, hb kept in a 5-deep rolling
        //      f64 register window (fully unrolled -> static indices) ----
        if (slot_active) {
            double w[5];
#pragma unroll
            for (int k = 0; k < HBS; ++k) {
                double acc = 0.0;
#pragma unroll
                for (int j = 0; j < 5; ++j)
                    acc += (double)gs[hr0 + k][scol + j] * GA[j];
                w[k % 5] = acc;              // hb row (hr0 + k)
                if (k >= 4) {
                    const int rb = k - 4;    // bl row offset in strip, 0..11
                    double a2 = 0.0;
#pragma unroll
                    for (int i = 0; i < 5; ++i)
                        a2 += w[(rb + i) % 5] * GA[i];   // hb[hr0+rb+i], i asc.
                    bl[hr0 + rb][scol] = (float)a2;      // stage-rounded f32
                }
            }
        }
        __syncthreads();

        // ---- next frame's gray loads issued early: global-load latency
        //      overlaps the LDS-bound Laplacian below (disjoint LDS arrays) ----
        if (s + 1 < SS) load_gray(s + 1);

        // ---- Laplacian, f64 accum over f32 blurred -> f32; running argmax ----
#pragma unroll
        for (int m = 0; m < 8; ++m) {
            int i = ty + 4 * m;   // local row
            double acc = 0.0;
#pragma unroll
            for (int di = 0; di < 5; ++di) {
                int rr = refl(r0 + i + di - 2, HH) - r0 + 2;
#pragma unroll
                for (int dj = 0; dj < 5; ++dj) {
                    if (LW[di][dj] != 0.0)
                        acc += (double)bl[rr][ccol[dj]] * LW[di][dj];
                }
            }
            float lap = (float)acc;  // lap materialized as f32
            if (lap > best[m]) { best[m] = lap; bidx[m] = s; }  // first max wins
        }
        __syncthreads();
    }

    // ---- gather: out[b,c,i,j] = x[b, best_s, c, i, j] ----
#pragma unroll
    for (int m = 0; m < 8; ++m) {
        int i = ty + 4 * m;
        int gi = r0 + i;
        int gj = c0 + tx;
        size_t off = (size_t)gi * WW + gj;
        const float* xs = x + (size_t)((b * SS + bidx[m]) * CC) * HW + off;
        float* op = out + (size_t)(b * CC) * HW + off;
        op[0]      = xs[0];
        op[HW]     = xs[HW];
        op[2 * HW] = xs[2 * HW];
    }
}

extern "C" void kernel_launch(void* const* d_in, const int* in_sizes, int n_in,
                              void* d_out, int out_size, void* d_ws, size_t ws_size,
                              hipStream_t stream) {
    (void)in_sizes; (void)n_in; (void)d_ws; (void)ws_size; (void)out_size;
    const float* x = (const float*)d_in[0];
    float* out = (float*)d_out;
    dim3 grid(BB * (HH / TH) * (WW / TW));  // 2048
    dim3 block(256);
    hipLaunchKernelGGL(lap_focus_fused, grid, block, 0, stream, x, out);
}